// Round 12
// baseline (320.835 us; speedup 1.0000x reference)
//
#include <hip/hip_runtime.h>
#include <hip/hip_bf16.h>

#define TT 2048
#define BB 4
#define HH 8
#define KK 256
#define MM (BB*TT)      // 8192 tokens
#define NQKV 6144
#define QKS 4096        // packed Q|K row stride

typedef __attribute__((ext_vector_type(8))) short bf16x8;
typedef __attribute__((ext_vector_type(4))) float f32x4;
typedef __attribute__((ext_vector_type(16))) float f32x16;

__device__ __forceinline__ void gld_lds16(const void* g, void* lds) {
    __builtin_amdgcn_global_load_lds(
        (const __attribute__((address_space(1))) unsigned int*)g,
        (__attribute__((address_space(3))) unsigned int*)lds, 16, 0, 0);
}

__device__ __forceinline__ unsigned pkbf(float a, float b) {
    return (unsigned)__bfloat16_as_ushort(__float2bfloat16(a))
         | ((unsigned)__bfloat16_as_ushort(__float2bfloat16(b)) << 16);
}

// ---------------- convert fp32 -> bf16 (vectorized) ----------------
__global__ __launch_bounds__(256) void cvt_k(const float* __restrict__ in,
                                             __hip_bfloat16* __restrict__ out, int n) {
    int i = (blockIdx.x * 256 + threadIdx.x) * 4;
    if (i + 3 < n) {
        float4 v = *(const float4*)(in + i);
        out[i + 0] = __float2bfloat16(v.x);
        out[i + 1] = __float2bfloat16(v.y);
        out[i + 2] = __float2bfloat16(v.z);
        out[i + 3] = __float2bfloat16(v.w);
    }
}

// ---------------- transpose + convert: in (R,C) f32 -> out (C,R) bf16 ----------------
__global__ __launch_bounds__(256) void transpose_cvt(const float* __restrict__ in,
                                                     __hip_bfloat16* __restrict__ out,
                                                     int R, int C) {
    __shared__ float tile[32][33];
    int c0 = blockIdx.x * 32, r0 = blockIdx.y * 32;
    int tx = threadIdx.x & 31, ty = threadIdx.x >> 5;   // ty 0..7
    #pragma unroll
    for (int i = ty; i < 32; i += 8)
        tile[i][tx] = in[(size_t)(r0 + i) * C + c0 + tx];
    __syncthreads();
    #pragma unroll
    for (int i = ty; i < 32; i += 8)
        out[(size_t)(c0 + i) * R + r0 + tx] = __float2bfloat16(tile[tx][i]);
}

// ---------------- GEMM, 2-phase pipelined + swizzled LDS ----------------
// (round-8 proven version, unchanged)
template<int EPI, int BN>
__global__ __launch_bounds__(256) void gemm_k(const __hip_bfloat16* __restrict__ A,
                                              const __hip_bfloat16* __restrict__ Bt,
                                              int M, int N, int Kd,
                                              const float* __restrict__ bias,
                                              const float* __restrict__ res,
                                              void* __restrict__ outp, float scale,
                                              __hip_bfloat16* __restrict__ vtp) {
    __shared__ short sA[2][128 * 32];
    __shared__ short sB[2][BN * 32];
    int tid = threadIdx.x, lane = tid & 63, wave = tid >> 6;
    int l15 = lane & 15, g = lane >> 4;
    int m0 = blockIdx.y * 128, n0 = blockIdx.x * BN;
    constexpr int NF = BN / 32;
    int wm = (wave >> 1) * 64, wn = (wave & 1) * (BN / 2);
    f32x4 acc[4][NF] = {};
    const int NT = Kd >> 5;

    int arow0 = tid >> 2;
    int arow1 = arow0 + 64;
    int sl = ((tid & 3) ^ ((arow0 >> 1) & 3)) * 8;   // swizzled source slot (elements)

    auto STAGE = [&](int kt, int buf) {
        size_t ka = (size_t)kt * 32 + sl;
        gld_lds16(A + (size_t)(m0 + arow0) * Kd + ka, (char*)sA[buf] + wave * 1024);
        gld_lds16(A + (size_t)(m0 + arow1) * Kd + ka, (char*)sA[buf] + 4096 + wave * 1024);
        gld_lds16(Bt + (size_t)(n0 + arow0) * Kd + ka, (char*)sB[buf] + wave * 1024);
        if (BN == 128)
            gld_lds16(Bt + (size_t)(n0 + arow1) * Kd + ka, (char*)sB[buf] + 4096 + wave * 1024);
    };

    STAGE(0, 0);
    asm volatile("s_waitcnt vmcnt(0)" ::: "memory");
    __syncthreads();
    int cur = 0;
    for (int kt = 0; kt < NT; ++kt) {
        if (kt + 1 < NT) STAGE(kt + 1, cur ^ 1);   // issue next tile early
        bf16x8 af[4], bfr[NF];
        #pragma unroll
        for (int mf = 0; mf < 4; ++mf) {
            int row = wm + mf * 16 + l15;
            af[mf] = *(const bf16x8*)((char*)sA[cur] + row * 64 + ((g ^ ((row >> 1) & 3)) * 16));
        }
        #pragma unroll
        for (int nf = 0; nf < NF; ++nf) {
            int row = wn + nf * 16 + l15;
            bfr[nf] = *(const bf16x8*)((char*)sB[cur] + row * 64 + ((g ^ ((row >> 1) & 3)) * 16));
        }
        #pragma unroll
        for (int mf = 0; mf < 4; ++mf)
            #pragma unroll
            for (int nf = 0; nf < NF; ++nf)
                acc[mf][nf] = __builtin_amdgcn_mfma_f32_16x16x32_bf16(af[mf], bfr[nf], acc[mf][nf], 0, 0, 0);
        asm volatile("s_waitcnt vmcnt(0)" ::: "memory");   // next tile landed
        __syncthreads();                                    // all waves done with cur
        cur ^= 1;
    }

    #pragma unroll
    for (int mf = 0; mf < 4; ++mf) {
        int rowb = m0 + wm + mf * 16 + g * 4;
        #pragma unroll
        for (int nf = 0; nf < NF; ++nf) {
            int col = n0 + wn + nf * 16 + l15;
            if (EPI == 0) {
                if (col < 4096) {
                    #pragma unroll
                    for (int r = 0; r < 4; ++r)
                        ((__hip_bfloat16*)outp)[(size_t)(rowb + r) * QKS + col] =
                            __float2bfloat16(acc[mf][nf][r] * scale);
                } else {
                    int hv = col - 4096, h = hv >> 8, d = hv & 255;
                    int b = rowb >> 11, t = rowb & 2047;
                    ushort4 w;
                    w.x = __bfloat16_as_ushort(__float2bfloat16(acc[mf][nf][0]));
                    w.y = __bfloat16_as_ushort(__float2bfloat16(acc[mf][nf][1]));
                    w.z = __bfloat16_as_ushort(__float2bfloat16(acc[mf][nf][2]));
                    w.w = __bfloat16_as_ushort(__float2bfloat16(acc[mf][nf][3]));
                    *(ushort4*)(vtp + ((size_t)((b * 8 + h) * 256 + d)) * TT + t) = w;
                }
            } else {
                #pragma unroll
                for (int r = 0; r < 4; ++r) {
                    float v = acc[mf][nf][r];
                    size_t idx = (size_t)(rowb + r) * N + col;
                    if (EPI == 1) {
                        ((float*)outp)[idx] = v + bias[col] + res[idx];
                    } else {
                        v += bias[col];
                        ((__hip_bfloat16*)outp)[idx] = __float2bfloat16(v > 0.0f ? v : 0.0f);
                    }
                }
            }
        }
    }
}

// ---------------- flash attention: 4 waves x 32 q-rows, 32x32x16 MFMA, in-reg P ----
// 512 blocks, target 2/CU (LDS exactly 65536 B = K 32KB + V 32KB, no P tile).
// All 4 waves share one 128-row q-tile; heavy tiles (jt 15..8) dispatch first.
// Swapped QK^T: mfma(A=K, B=Q) -> lane l31 owns one q-col; softmax lane-local.
// P redistributed IN-REGISTER (T12): pack S into bf16 octet-words, exchange
// hi-halves via shfl_xor(32), cndmask-select into PV A-fragments. No Pl LDS.
// K LDS [64 s][512 B]: granule g holds K[s][g ^ (s&31)] -> 2-way banks (free).
// V LDS [64 R][512 B]: 4 d-rows per row (d = (gl>>3)*64+R, gl = g^(R&31)).
__global__ __launch_bounds__(256, 1) void attn_k(const __hip_bfloat16* __restrict__ QK,
                                                 const __hip_bfloat16* __restrict__ VT,
                                                 __hip_bfloat16* __restrict__ O) {
    __shared__ char Kl[32768];
    __shared__ char Vl[32768];
    int tid = threadIdx.x, lane = tid & 63, wave = tid >> 6;
    int l31 = lane & 31, hi = lane >> 5;
    int id = blockIdx.x;
    int xcd = id & 7, w = id >> 3;            // w: 0..63
    int half = w >> 5, w5 = w & 31;
    int bh = xcd * 4 + (w5 & 3);
    int jt = half ? (w5 >> 2) : 15 - (w5 >> 2);
    int b = bh >> 3, h = bh & 7;
    const __hip_bfloat16* Qb = QK + (size_t)b * TT * QKS + h * KK;
    const __hip_bfloat16* Kb = Qb + 2048;
    const __hip_bfloat16* Vtb = VT + (size_t)bh * KK * TT;

    int q0 = jt * 128;
    int rowbase = q0 + wave * 32;
    int qg = rowbase + l31;                   // this lane's q-row

    // Q fragments (B-operand): qf[ks] = Q[qg][ks*16 + hi*8 .. +8]
    bf16x8 qf[16];
    #pragma unroll
    for (int ks = 0; ks < 16; ++ks)
        qf[ks] = *(const bf16x8*)(Qb + (size_t)qg * QKS + ks * 16 + hi * 8);

    auto STAGE = [&](int s0) {
        #pragma unroll
        for (int i = 0; i < 8; ++i) {         // K: 64 rows x 512 B
            int L = i * 4096 + tid * 16;
            int r = L >> 9;
            int gI = (L >> 4) & 31;
            gld_lds16((const char*)(Kb + (size_t)(s0 + r) * QKS) + ((gI ^ (r & 31)) << 4),
                      Kl + i * 4096 + wave * 1024);
        }
        #pragma unroll
        for (int i = 0; i < 8; ++i) {         // V: [64 R][512 B], 4 d-rows packed
            int L = i * 4096 + tid * 16;
            int R = L >> 9;
            int gI = (L >> 4) & 31;
            int sv = gI ^ (R & 31);
            int d = (sv >> 3) * 64 + R;
            gld_lds16((const char*)(Vtb + (size_t)d * TT + s0 + (sv & 7) * 8),
                      Vl + i * 4096 + wave * 1024);
        }
    };

    f32x16 Oa[8] = {};
    float mrow = -__builtin_inff();
    float lrow = 0.f;
    const int niter = 2 * jt + 2;

    #pragma unroll 1
    for (int i = 0; i < niter; ++i) {
        int s0 = i * 64;
        STAGE(s0);
        asm volatile("s_waitcnt vmcnt(0)" ::: "memory");
        __syncthreads();                              // tile ready

        if (s0 <= rowbase + 31) {                     // wave has unmasked rows
            #pragma unroll
            for (int st = 0; st < 2; ++st) {
                // ---- QK^T swapped: S = K(32s x 256k) x Q -> D[s][q], lane col = q
                f32x16 S = {};
                int r = st * 32 + l31;
                int rsw = r & 31;
                __builtin_amdgcn_s_setprio(1);
                #pragma unroll
                for (int ks = 0; ks < 16; ++ks) {
                    bf16x8 kf = *(const bf16x8*)(Kl + r * 512 + (((2 * ks + hi) ^ rsw) << 4));
                    S = __builtin_amdgcn_mfma_f32_32x32x16_bf16(kf, qf[ks], S, 0, 0, 0);
                }
                __builtin_amdgcn_s_setprio(0);
                // ---- causal mask: s-row of reg r2 = (r2&3)+8*(r2>>2)+4*hi, q-col = qg
                if (s0 + st * 32 + 31 > qg - 31) {    // tile may overlap diagonal
                    #pragma unroll
                    for (int r2 = 0; r2 < 16; ++r2) {
                        int sg = s0 + st * 32 + (r2 & 3) + ((r2 >> 2) << 3) + hi * 4;
                        if (sg > qg) S[r2] = -__builtin_inff();
                    }
                }
                // ---- online softmax (exp2 domain), lane-local per q + 1 shfl
                float mx = S[0];
                #pragma unroll
                for (int r2 = 1; r2 < 16; ++r2) mx = fmaxf(mx, S[r2]);
                mx = fmaxf(mx, __shfl_xor(mx, 32));
                if (__any(mx > mrow + 8.0f)) {        // defer-max rescale
                    float mn = fmaxf(mrow, mx);
                    float alpha = exp2f(mrow - mn);
                    mrow = mn;
                    lrow *= alpha;
                    #pragma unroll
                    for (int r2 = 0; r2 < 16; ++r2) {
                        float al = __shfl(alpha, (r2 & 3) + ((r2 >> 2) << 3) + hi * 4);
                        #pragma unroll
                        for (int dt = 0; dt < 8; ++dt) Oa[dt][r2] *= al;
                    }
                }
                float ps = 0.f;
                #pragma unroll
                for (int r2 = 0; r2 < 16; ++r2) {
                    float p = exp2f(S[r2] - mrow);
                    S[r2] = p; ps += p;
                }
                ps += __shfl_xor(ps, 32);
                lrow += ps;
                // ---- in-register P: pack 4 octet-groups (2 words each)
                // producer lane (l31=q, hi): octet g2 covers s = 8*g2 + 4*hi + 0..3
                unsigned Pw[8];
                #pragma unroll
                for (int g2 = 0; g2 < 4; ++g2) {
                    Pw[g2 * 2 + 0] = pkbf(S[g2 * 4 + 0], S[g2 * 4 + 1]);
                    Pw[g2 * 2 + 1] = pkbf(S[g2 * 4 + 2], S[g2 * 4 + 3]);
                }
                // ---- assemble PV A-frags: consumer (hi, ks2) needs octet 2ks2+hi,
                // elems 0..3 from hi0-producer, 4..7 from hi1-producer
                bf16x8 pa[2];
                #pragma unroll
                for (int ks2 = 0; ks2 < 2; ++ks2) {
                    unsigned own0 = Pw[(2 * ks2) * 2 + 0],     own1 = Pw[(2 * ks2) * 2 + 1];
                    unsigned oth0 = Pw[(2 * ks2 + 1) * 2 + 0], oth1 = Pw[(2 * ks2 + 1) * 2 + 1];
                    unsigned pw0a = (unsigned)__shfl_xor((int)own0, 32);  // partner P[2ks2]
                    unsigned pw0b = (unsigned)__shfl_xor((int)own1, 32);
                    unsigned pw1a = (unsigned)__shfl_xor((int)oth0, 32);  // partner P[2ks2+1]
                    unsigned pw1b = (unsigned)__shfl_xor((int)oth1, 32);
                    union { unsigned u[4]; bf16x8 v; } pu;
                    pu.u[0] = hi ? pw1a : own0;
                    pu.u[1] = hi ? pw1b : own1;
                    pu.u[2] = hi ? oth0 : pw0a;
                    pu.u[3] = hi ? oth1 : pw0b;
                    pa[ks2] = pu.v;
                }
                // ---- PV: O[32q][256d] += P[32q][32s] x V[32s][256d]
                __builtin_amdgcn_s_setprio(1);
                #pragma unroll
                for (int dt = 0; dt < 8; ++dt) {
                    int R = (dt & 1) * 32 + l31;
                    int Rsw = R & 31;
                    #pragma unroll
                    for (int ks2 = 0; ks2 < 2; ++ks2) {
                        int lg = ((dt >> 1) << 3) + 4 * st + 2 * ks2 + hi;
                        bf16x8 vb = *(const bf16x8*)(Vl + R * 512 + ((lg ^ Rsw) << 4));
                        Oa[dt] = __builtin_amdgcn_mfma_f32_32x32x16_bf16(pa[ks2], vb, Oa[dt], 0, 0, 0);
                    }
                }
                __builtin_amdgcn_s_setprio(0);
            }
        }
        __syncthreads();                              // all waves done before restage
    }
    // ---- epilogue: divide by lrow (per-q, via shfl) and store
    float rcp_ = 1.0f / lrow;
    #pragma unroll
    for (int r2 = 0; r2 < 16; ++r2) {
        int crow = (r2 & 3) + ((r2 >> 2) << 3) + hi * 4;
        float rc = __shfl(rcp_, crow);
        int t = rowbase + crow;
        __hip_bfloat16* op = O + ((size_t)b * TT + t) * 2048 + h * KK + l31;
        #pragma unroll
        for (int dt = 0; dt < 8; ++dt)
            op[dt * 32] = __float2bfloat16(Oa[dt][r2] * rc);
    }
}

// ---------------- row LayerNorm over K=256, 4 rows/block ----------------
__global__ __launch_bounds__(256) void layernorm_k(const float* __restrict__ y,
                                                   const float* __restrict__ g,
                                                   const float* __restrict__ be,
                                                   float* __restrict__ out_f,
                                                   __hip_bfloat16* __restrict__ out_b) {
    int row = blockIdx.x * 4 + (threadIdx.x >> 6);
    int lane = threadIdx.x & 63;
    float4 v = *(const float4*)(y + (size_t)row * 256 + lane * 4);
    float s = v.x + v.y + v.z + v.w;
    #pragma unroll
    for (int d = 1; d < 64; d <<= 1) s += __shfl_xor(s, d);
    float mu = s * (1.0f / 256.0f);
    float dx = v.x - mu, dy = v.y - mu, dz = v.z - mu, dw = v.w - mu;
    float q = dx * dx + dy * dy + dz * dz + dw * dw;
    #pragma unroll
    for (int d = 1; d < 64; d <<= 1) q += __shfl_xor(q, d);
    float rs = rsqrtf(q * (1.0f / 256.0f) + 1e-5f);
    float4 gg = *(const float4*)(g + lane * 4);
    float4 bb = *(const float4*)(be + lane * 4);
    float4 o;
    o.x = dx * rs * gg.x + bb.x;
    o.y = dy * rs * gg.y + bb.y;
    o.z = dz * rs * gg.z + bb.z;
    o.w = dw * rs * gg.w + bb.w;
    *(float4*)(out_f + (size_t)row * 256 + lane * 4) = o;
    if (out_b) {
        size_t i = (size_t)row * 256 + lane * 4;
        out_b[i + 0] = __float2bfloat16(o.x);
        out_b[i + 1] = __float2bfloat16(o.y);
        out_b[i + 2] = __float2bfloat16(o.z);
        out_b[i + 3] = __float2bfloat16(o.w);
    }
}

extern "C" void kernel_launch(void* const* d_in, const int* in_sizes, int n_in,
                              void* d_out, int out_size, void* d_ws, size_t ws_size,
                              hipStream_t stream) {
    const float* x  = (const float*)d_in[0];
    const float* wq = (const float*)d_in[1];
    const float* wk = (const float*)d_in[2];
    const float* wv = (const float*)d_in[3];
    const float* wu = (const float*)d_in[4];
    const float* bu = (const float*)d_in[5];
    const float* w1 = (const float*)d_in[6];
    const float* b1 = (const float*)d_in[7];
    const float* w2 = (const float*)d_in[8];
    const float* b2 = (const float*)d_in[9];
    const float* g1 = (const float*)d_in[10];
    const float* be1 = (const float*)d_in[11];
    const float* g2 = (const float*)d_in[12];
    const float* be2 = (const float*)d_in[13];

    char* p = (char*)d_ws;
    auto alloc = [&](size_t bytes) { char* r = p; p += bytes; return r; };
    __hip_bfloat16* xb    = (__hip_bfloat16*)alloc((size_t)MM * KK * 2);
    __hip_bfloat16* wqkvT = (__hip_bfloat16*)alloc((size_t)NQKV * KK * 2);
    __hip_bfloat16* wuT   = (__hip_bfloat16*)alloc((size_t)KK * 2048 * 2);
    __hip_bfloat16* w1T   = (__hip_bfloat16*)alloc((size_t)1024 * KK * 2);
    __hip_bfloat16* w2T   = (__hip_bfloat16*)alloc((size_t)KK * 1024 * 2);
    __hip_bfloat16* qk    = (__hip_bfloat16*)alloc((size_t)MM * QKS * 2);
    __hip_bfloat16* vt    = (__hip_bfloat16*)alloc((size_t)32 * KK * TT * 2);
    __hip_bfloat16* attn  = (__hip_bfloat16*)alloc((size_t)MM * 2048 * 2);
    float*          y1    = (float*)alloc((size_t)MM * KK * 4);
    float*          x1    = (float*)alloc((size_t)MM * KK * 4);
    __hip_bfloat16* x1b   = (__hip_bfloat16*)alloc((size_t)MM * KK * 2);
    __hip_bfloat16* hid   = (__hip_bfloat16*)alloc((size_t)MM * 1024 * 2);
    float*          y2    = (float*)alloc((size_t)MM * KK * 4);

    cvt_k<<<(MM * KK) / 1024, 256, 0, stream>>>(x, xb, MM * KK);
    transpose_cvt<<<dim3(64, 8),  256, 0, stream>>>(wq, wqkvT,             256, 2048);
    transpose_cvt<<<dim3(64, 8),  256, 0, stream>>>(wk, wqkvT + 2048 * 256, 256, 2048);
    transpose_cvt<<<dim3(64, 8),  256, 0, stream>>>(wv, wqkvT + 4096 * 256, 256, 2048);
    transpose_cvt<<<dim3(8, 64),  256, 0, stream>>>(wu, wuT, 2048, 256);
    transpose_cvt<<<dim3(32, 8),  256, 0, stream>>>(w1, w1T, 256, 1024);
    transpose_cvt<<<dim3(8, 32),  256, 0, stream>>>(w2, w2T, 1024, 256);

    // QKV projection; q/k scale 0.25*sqrt(log2 e); V fused-transposed into vt
    gemm_k<0, 128><<<dim3(NQKV / 128, MM / 128), 256, 0, stream>>>(
        xb, wqkvT, MM, NQKV, 256, nullptr, nullptr, qk, 0.3002806f, vt);

    attn_k<<<dim3(512), 256, 0, stream>>>(qk, vt, attn);

    gemm_k<1, 64><<<dim3(4, MM / 128), 256, 0, stream>>>(
        attn, wuT, MM, 256, 2048, bu, x, y1, 1.0f, nullptr);
    layernorm_k<<<MM / 4, 256, 0, stream>>>(y1, g1, be1, x1, x1b);

    gemm_k<2, 128><<<dim3(8, MM / 128), 256, 0, stream>>>(
        x1b, w1T, MM, 1024, 256, b1, nullptr, hid, 1.0f, nullptr);
    gemm_k<1, 64><<<dim3(4, MM / 128), 256, 0, stream>>>(
        hid, w2T, MM, 256, 1024, b2, x1, y2, 1.0f, nullptr);
    layernorm_k<<<MM / 4, 256, 0, stream>>>(y2, g2, be2, (float*)d_out, nullptr);
}

// Round 13
// 259.064 us; speedup vs baseline: 1.2384x; 1.2384x over previous
//
#include <hip/hip_runtime.h>
#include <hip/hip_bf16.h>

#define TT 2048
#define BB 4
#define HH 8
#define KK 256
#define MM (BB*TT)      // 8192 tokens
#define NQKV 6144
#define QKS 4096        // packed Q|K row stride

typedef __attribute__((ext_vector_type(8))) short bf16x8;
typedef __attribute__((ext_vector_type(4))) float f32x4;

__device__ __forceinline__ void gld_lds16(const void* g, void* lds) {
    __builtin_amdgcn_global_load_lds(
        (const __attribute__((address_space(1))) unsigned int*)g,
        (__attribute__((address_space(3))) unsigned int*)lds, 16, 0, 0);
}

// ---------------- convert fp32 -> bf16 (vectorized) ----------------
__global__ __launch_bounds__(256) void cvt_k(const float* __restrict__ in,
                                             __hip_bfloat16* __restrict__ out, int n) {
    int i = (blockIdx.x * 256 + threadIdx.x) * 4;
    if (i + 3 < n) {
        float4 v = *(const float4*)(in + i);
        out[i + 0] = __float2bfloat16(v.x);
        out[i + 1] = __float2bfloat16(v.y);
        out[i + 2] = __float2bfloat16(v.z);
        out[i + 3] = __float2bfloat16(v.w);
    }
}

// ---------------- transpose + convert: in (R,C) f32 -> out (C,R) bf16 ----------------
__global__ __launch_bounds__(256) void transpose_cvt(const float* __restrict__ in,
                                                     __hip_bfloat16* __restrict__ out,
                                                     int R, int C) {
    __shared__ float tile[32][33];
    int c0 = blockIdx.x * 32, r0 = blockIdx.y * 32;
    int tx = threadIdx.x & 31, ty = threadIdx.x >> 5;   // ty 0..7
    #pragma unroll
    for (int i = ty; i < 32; i += 8)
        tile[i][tx] = in[(size_t)(r0 + i) * C + c0 + tx];
    __syncthreads();
    #pragma unroll
    for (int i = ty; i < 32; i += 8)
        out[(size_t)(c0 + i) * R + r0 + tx] = __float2bfloat16(tile[tx][i]);
}

// ---------------- GEMM, 2-phase pipelined, BK=64, packed-512B-row LDS ----------------
// Double-buffered LDS staged via global_load_lds (dest linear, inverse perm on
// GLOBAL source). Tile rows packed 4-per-512B-physical-row with full XOR swizzle
// v = vp ^ phys -> bank quad = c ^ (row&7): 2-way = free. BK=64 halves the
// barrier/vmcnt count vs BK=32 at identical bytes.
// EPI 0: QKV fused epilogue: col<4096 -> qk (stride 4096, *scale);
//        col>=4096 -> V transposed into vt (B*H, 256, T)
// EPI 1: out f32 = acc + bias[col] + res[idx]
// EPI 2: out bf16 = relu(acc + bias[col])
template<int EPI, int BN>
__global__ __launch_bounds__(256) void gemm_k(const __hip_bfloat16* __restrict__ A,
                                              const __hip_bfloat16* __restrict__ Bt,
                                              int M, int N, int Kd,
                                              const float* __restrict__ bias,
                                              const float* __restrict__ res,
                                              void* __restrict__ outp, float scale,
                                              __hip_bfloat16* __restrict__ vtp) {
    constexpr int NF = BN / 32;
    constexpr int BPHYS = BN / 4;        // physical 512-B rows in B tile
    __shared__ short sA[2][128 * 64];    // 16 KB per buffer
    __shared__ short sB[2][BN * 64];
    int tid = threadIdx.x, lane = tid & 63, wave = tid >> 6;
    int l15 = lane & 15, g = lane >> 4;
    int m0 = blockIdx.y * 128, n0 = blockIdx.x * BN;
    int wm = (wave >> 1) * 64, wn = (wave & 1) * (BN / 2);
    f32x4 acc[4][NF] = {};
    const int NT = Kd >> 6;

    auto STAGE = [&](int kt, int buf) {
        #pragma unroll
        for (int c = 0; c < 4; ++c) {            // A: 128 rows x 128 B = 16 KB
            int L = c * 4096 + tid * 16;
            int phys = L >> 9;                   // 0..31
            int vp = ((L >> 4) & 31) ^ phys;     // unswizzled slot
            int row = (vp >> 3) * 32 + phys;
            gld_lds16(A + (size_t)(m0 + row) * Kd + kt * 64 + (vp & 7) * 8,
                      (char*)sA[buf] + L);
        }
        #pragma unroll
        for (int c = 0; c < BN / 32; ++c) {      // B: BN rows x 128 B
            int L = c * 4096 + tid * 16;
            int phys = L >> 9;                   // 0..BPHYS-1
            int vp = ((L >> 4) & 31) ^ phys;
            int row = (vp >> 3) * BPHYS + phys;
            gld_lds16(Bt + (size_t)(n0 + row) * Kd + kt * 64 + (vp & 7) * 8,
                      (char*)sB[buf] + L);
        }
    };

    STAGE(0, 0);
    asm volatile("s_waitcnt vmcnt(0)" ::: "memory");
    __syncthreads();
    int cur = 0;
    for (int kt = 0; kt < NT; ++kt) {
        if (kt + 1 < NT) STAGE(kt + 1, cur ^ 1);   // issue next tile early
        #pragma unroll
        for (int kk = 0; kk < 2; ++kk) {
            bf16x8 af[4], bfr[NF];
            #pragma unroll
            for (int mf = 0; mf < 4; ++mf) {
                int R = wm + mf * 16 + l15;
                int v = (((R >> 5) << 3) + (kk << 2) + g) ^ (R & 31);
                af[mf] = *(const bf16x8*)((char*)sA[cur] + ((R & 31) << 9) + (v << 4));
            }
            #pragma unroll
            for (int nf = 0; nf < NF; ++nf) {
                int R = wn + nf * 16 + l15;
                int v = ((R / BPHYS) * 8 + (kk << 2) + g) ^ (R & (BPHYS - 1));
                bfr[nf] = *(const bf16x8*)((char*)sB[cur] + ((R & (BPHYS - 1)) << 9) + (v << 4));
            }
            #pragma unroll
            for (int mf = 0; mf < 4; ++mf)
                #pragma unroll
                for (int nf = 0; nf < NF; ++nf)
                    acc[mf][nf] = __builtin_amdgcn_mfma_f32_16x16x32_bf16(af[mf], bfr[nf], acc[mf][nf], 0, 0, 0);
        }
        asm volatile("s_waitcnt vmcnt(0)" ::: "memory");   // next tile landed
        __syncthreads();                                    // all waves done with cur
        cur ^= 1;
    }

    #pragma unroll
    for (int mf = 0; mf < 4; ++mf) {
        int rowb = m0 + wm + mf * 16 + g * 4;
        #pragma unroll
        for (int nf = 0; nf < NF; ++nf) {
            int col = n0 + wn + nf * 16 + l15;
            if (EPI == 0) {
                if (col < 4096) {
                    #pragma unroll
                    for (int r = 0; r < 4; ++r)
                        ((__hip_bfloat16*)outp)[(size_t)(rowb + r) * QKS + col] =
                            __float2bfloat16(acc[mf][nf][r] * scale);
                } else {
                    int hv = col - 4096, h = hv >> 8, d = hv & 255;
                    int b = rowb >> 11, t = rowb & 2047;
                    ushort4 w;
                    w.x = __bfloat16_as_ushort(__float2bfloat16(acc[mf][nf][0]));
                    w.y = __bfloat16_as_ushort(__float2bfloat16(acc[mf][nf][1]));
                    w.z = __bfloat16_as_ushort(__float2bfloat16(acc[mf][nf][2]));
                    w.w = __bfloat16_as_ushort(__float2bfloat16(acc[mf][nf][3]));
                    *(ushort4*)(vtp + ((size_t)((b * 8 + h) * 256 + d)) * TT + t) = w;
                }
            } else {
                #pragma unroll
                for (int r = 0; r < 4; ++r) {
                    float v = acc[mf][nf][r];
                    size_t idx = (size_t)(rowb + r) * N + col;
                    if (EPI == 1) {
                        ((float*)outp)[idx] = v + bias[col] + res[idx];
                    } else {
                        v += bias[col];
                        ((__hip_bfloat16*)outp)[idx] = __float2bfloat16(v > 0.0f ? v : 0.0f);
                    }
                }
            }
        }
    }
}

// ---------------- flash attention: 8 waves x 16 q-rows, dbuf LDS, swapped-QK softmax ----
// (round-8 proven version, verbatim: 125 us, VGPR 116, no spill)
__global__ __launch_bounds__(512, 2) void attn_k(const __hip_bfloat16* __restrict__ QK,
                                                 const __hip_bfloat16* __restrict__ VT,
                                                 __hip_bfloat16* __restrict__ O) {
    __shared__ char Kl[2][32768];
    __shared__ char Vl[2][32768];
    __shared__ char Pl[8][2048];     // per-wave P: [16 q][64 s] bf16, XOR-swizzled
    int tid = threadIdx.x, lane = tid & 63, wave = tid >> 6;
    int id = blockIdx.x;
    int xcd = id & 7, w = id >> 3;            // w: 0..31
    int bh = xcd * 4 + (w >> 3);
    int jtp = w & 7;
    int b = bh >> 3, h = bh & 7;
    const __hip_bfloat16* Qb = QK + (size_t)b * TT * QKS + h * KK;
    const __hip_bfloat16* Kb = Qb + 2048;
    const __hip_bfloat16* Vtb = VT + (size_t)bh * KK * TT;

    int l15 = lane & 15, g = lane >> 4;
    int koff = g * 8;            // elements
    int koffB = g * 16;          // bytes
    int pswz = (l15 & 7) << 4;   // P-tile swizzle for this lane's q-row

    auto STAGE = [&](int s0, int buf) {
        #pragma unroll
        for (int rd = 0; rd < 4; ++rd) {        // K: 64 rows x 512 B
            int L = rd * 8192 + tid * 16;
            int row = L >> 9;
            int cb = (L & 511) ^ ((row & 7) << 4);
            gld_lds16((const char*)(Kb + (size_t)(s0 + row) * QKS) + cb,
                      Kl[buf] + rd * 8192 + wave * 1024);
        }
        #pragma unroll
        for (int rd = 0; rd < 4; ++rd) {        // V: 256 rows x 128 B
            int L = rd * 8192 + tid * 16;
            int row = L >> 7;
            int cb = (L & 127) ^ ((row & 7) << 4);
            gld_lds16((const char*)(Vtb + (size_t)row * TT + s0) + cb,
                      Vl[buf] + rd * 8192 + wave * 1024);
        }
    };

    #pragma unroll 1
    for (int half = 0; half < 2; ++half) {
        int jt = (half == 0) ? jtp : 15 - jtp;
        int q0 = jt * 128;
        int rowbase = q0 + wave * 16;
        bf16x8 qf[8];
        #pragma unroll
        for (int kk = 0; kk < 8; ++kk)
            qf[kk] = *(const bf16x8*)(Qb + (size_t)(rowbase + l15) * QKS + kk * 32 + koff);

        f32x4 Oa[16] = {};
        float mrow = -__builtin_inff();
        float lrow = 0.f;

        STAGE(0, 0);
        asm volatile("s_waitcnt vmcnt(0)" ::: "memory");
        __syncthreads();
        int cur = 0;
        const int niter = 2 * jt + 2;

        #pragma unroll 1
        for (int i = 0; i < niter; ++i) {
            int s0 = i * 64;
            if (i + 1 < niter) STAGE(s0 + 64, cur ^ 1);   // prefetch into other buffer

            if (s0 <= rowbase + 15) {                     // wave has unmasked rows
                // ---- QK^T swapped: S = K-tile x Q-frag (lane col = q = l15)
                f32x4 S[4] = {};
                __builtin_amdgcn_s_setprio(1);
                #pragma unroll
                for (int nf = 0; nf < 4; ++nf) {
                    int r = nf * 16 + l15;
                    int swz = (r & 7) << 4;
                    #pragma unroll
                    for (int kk = 0; kk < 8; ++kk) {
                        bf16x8 kf = *(const bf16x8*)(Kl[cur] + r * 512 + ((kk * 64 + koffB) ^ swz));
                        S[nf] = __builtin_amdgcn_mfma_f32_16x16x32_bf16(kf, qf[kk], S[nf], 0, 0, 0);
                    }
                }
                __builtin_amdgcn_s_setprio(0);
                if (s0 + 63 > rowbase) {                  // causal: S row = s, col = q
                    int qg = rowbase + l15;
                    #pragma unroll
                    for (int nf = 0; nf < 4; ++nf)
                        #pragma unroll
                        for (int r = 0; r < 4; ++r) {
                            int sg = s0 + nf * 16 + g * 4 + r;
                            if (sg > qg) S[nf][r] = -__builtin_inff();
                        }
                }
                // ---- softmax (exp2 domain), stats lane-local in l15
                float mx = S[0][0];
                #pragma unroll
                for (int nf = 0; nf < 4; ++nf)
                    #pragma unroll
                    for (int r = 0; r < 4; ++r) mx = fmaxf(mx, S[nf][r]);
                mx = fmaxf(mx, __shfl_xor(mx, 16));
                mx = fmaxf(mx, __shfl_xor(mx, 32));
                if (__any(mx > mrow + 8.0f)) {            // defer-max rescale
                    float mn = fmaxf(mrow, mx);
                    float alpha = exp2f(mrow - mn);
                    mrow = mn;
                    lrow *= alpha;
                    float al[4];
                    #pragma unroll
                    for (int r = 0; r < 4; ++r) al[r] = __shfl(alpha, (g << 2) + r);
                    #pragma unroll
                    for (int nf2 = 0; nf2 < 16; ++nf2)
                        #pragma unroll
                        for (int r = 0; r < 4; ++r) Oa[nf2][r] *= al[r];
                }
                float ps = 0.f;
                #pragma unroll
                for (int nf = 0; nf < 4; ++nf)
                    #pragma unroll
                    for (int r = 0; r < 4; ++r) {
                        float p = exp2f(S[nf][r] - mrow);
                        S[nf][r] = p; ps += p;
                    }
                ps += __shfl_xor(ps, 16);
                ps += __shfl_xor(ps, 32);
                lrow += ps;
                // ---- P -> LDS [q=l15][s], b64 packed writes, swizzled
                #pragma unroll
                for (int nf = 0; nf < 4; ++nf) {
                    uint2 pk2;
                    pk2.x = (unsigned)__bfloat16_as_ushort(__float2bfloat16(S[nf][0]))
                          | ((unsigned)__bfloat16_as_ushort(__float2bfloat16(S[nf][1])) << 16);
                    pk2.y = (unsigned)__bfloat16_as_ushort(__float2bfloat16(S[nf][2]))
                          | ((unsigned)__bfloat16_as_ushort(__float2bfloat16(S[nf][3])) << 16);
                    *(uint2*)(Pl[wave] + l15 * 128 + ((nf * 32 + g * 8) ^ pswz)) = pk2;
                }
                // ---- PV: O += P @ V
                bf16x8 pa[2];
                #pragma unroll
                for (int kk2 = 0; kk2 < 2; ++kk2)
                    pa[kk2] = *(const bf16x8*)(Pl[wave] + l15 * 128 + ((kk2 * 64 + koffB) ^ pswz));
                __builtin_amdgcn_s_setprio(1);
                #pragma unroll
                for (int nf2 = 0; nf2 < 16; ++nf2) {
                    int r = nf2 * 16 + l15;
                    int swz = (r & 7) << 4;
                    #pragma unroll
                    for (int kk2 = 0; kk2 < 2; ++kk2) {
                        bf16x8 vb = *(const bf16x8*)(Vl[cur] + r * 128 + ((kk2 * 64 + koffB) ^ swz));
                        Oa[nf2] = __builtin_amdgcn_mfma_f32_16x16x32_bf16(pa[kk2], vb, Oa[nf2], 0, 0, 0);
                    }
                }
                __builtin_amdgcn_s_setprio(0);
            }
            asm volatile("s_waitcnt vmcnt(0)" ::: "memory");   // own prefetch landed
            __syncthreads();                                    // all waves done + staged
            cur ^= 1;
        }
        // ---- write this q-tile's output
        float rcp_ = 1.0f / lrow;
        float rc[4];
        #pragma unroll
        for (int r = 0; r < 4; ++r) rc[r] = __shfl(rcp_, (g << 2) + r);
        #pragma unroll
        for (int nf2 = 0; nf2 < 16; ++nf2) {
            int col = nf2 * 16 + l15;
            #pragma unroll
            for (int r = 0; r < 4; ++r) {
                int t = rowbase + g * 4 + r;
                O[((size_t)b * TT + t) * 2048 + h * KK + col] = __float2bfloat16(Oa[nf2][r] * rc[r]);
            }
        }
    }
}

// ---------------- row LayerNorm over K=256, 4 rows/block ----------------
__global__ __launch_bounds__(256) void layernorm_k(const float* __restrict__ y,
                                                   const float* __restrict__ g,
                                                   const float* __restrict__ be,
                                                   float* __restrict__ out_f,
                                                   __hip_bfloat16* __restrict__ out_b) {
    int row = blockIdx.x * 4 + (threadIdx.x >> 6);
    int lane = threadIdx.x & 63;
    float4 v = *(const float4*)(y + (size_t)row * 256 + lane * 4);
    float s = v.x + v.y + v.z + v.w;
    #pragma unroll
    for (int d = 1; d < 64; d <<= 1) s += __shfl_xor(s, d);
    float mu = s * (1.0f / 256.0f);
    float dx = v.x - mu, dy = v.y - mu, dz = v.z - mu, dw = v.w - mu;
    float q = dx * dx + dy * dy + dz * dz + dw * dw;
    #pragma unroll
    for (int d = 1; d < 64; d <<= 1) q += __shfl_xor(q, d);
    float rs = rsqrtf(q * (1.0f / 256.0f) + 1e-5f);
    float4 gg = *(const float4*)(g + lane * 4);
    float4 bb = *(const float4*)(be + lane * 4);
    float4 o;
    o.x = dx * rs * gg.x + bb.x;
    o.y = dy * rs * gg.y + bb.y;
    o.z = dz * rs * gg.z + bb.z;
    o.w = dw * rs * gg.w + bb.w;
    *(float4*)(out_f + (size_t)row * 256 + lane * 4) = o;
    if (out_b) {
        size_t i = (size_t)row * 256 + lane * 4;
        out_b[i + 0] = __float2bfloat16(o.x);
        out_b[i + 1] = __float2bfloat16(o.y);
        out_b[i + 2] = __float2bfloat16(o.z);
        out_b[i + 3] = __float2bfloat16(o.w);
    }
}

extern "C" void kernel_launch(void* const* d_in, const int* in_sizes, int n_in,
                              void* d_out, int out_size, void* d_ws, size_t ws_size,
                              hipStream_t stream) {
    const float* x  = (const float*)d_in[0];
    const float* wq = (const float*)d_in[1];
    const float* wk = (const float*)d_in[2];
    const float* wv = (const float*)d_in[3];
    const float* wu = (const float*)d_in[4];
    const float* bu = (const float*)d_in[5];
    const float* w1 = (const float*)d_in[6];
    const float* b1 = (const float*)d_in[7];
    const float* w2 = (const float*)d_in[8];
    const float* b2 = (const float*)d_in[9];
    const float* g1 = (const float*)d_in[10];
    const float* be1 = (const float*)d_in[11];
    const float* g2 = (const float*)d_in[12];
    const float* be2 = (const float*)d_in[13];

    char* p = (char*)d_ws;
    auto alloc = [&](size_t bytes) { char* r = p; p += bytes; return r; };
    __hip_bfloat16* xb    = (__hip_bfloat16*)alloc((size_t)MM * KK * 2);
    __hip_bfloat16* wqkvT = (__hip_bfloat16*)alloc((size_t)NQKV * KK * 2);
    __hip_bfloat16* wuT   = (__hip_bfloat16*)alloc((size_t)KK * 2048 * 2);
    __hip_bfloat16* w1T   = (__hip_bfloat16*)alloc((size_t)1024 * KK * 2);
    __hip_bfloat16* w2T   = (__hip_bfloat16*)alloc((size_t)KK * 1024 * 2);
    __hip_bfloat16* qk    = (__hip_bfloat16*)alloc((size_t)MM * QKS * 2);
    __hip_bfloat16* vt    = (__hip_bfloat16*)alloc((size_t)32 * KK * TT * 2);
    __hip_bfloat16* attn  = (__hip_bfloat16*)alloc((size_t)MM * 2048 * 2);
    float*          y1    = (float*)alloc((size_t)MM * KK * 4);
    float*          x1    = (float*)alloc((size_t)MM * KK * 4);
    __hip_bfloat16* x1b   = (__hip_bfloat16*)alloc((size_t)MM * KK * 2);
    __hip_bfloat16* hid   = (__hip_bfloat16*)alloc((size_t)MM * 1024 * 2);
    float*          y2    = (float*)alloc((size_t)MM * KK * 4);

    cvt_k<<<(MM * KK) / 1024, 256, 0, stream>>>(x, xb, MM * KK);
    transpose_cvt<<<dim3(64, 8),  256, 0, stream>>>(wq, wqkvT,             256, 2048);
    transpose_cvt<<<dim3(64, 8),  256, 0, stream>>>(wk, wqkvT + 2048 * 256, 256, 2048);
    transpose_cvt<<<dim3(64, 8),  256, 0, stream>>>(wv, wqkvT + 4096 * 256, 256, 2048);
    transpose_cvt<<<dim3(8, 64),  256, 0, stream>>>(wu, wuT, 2048, 256);
    transpose_cvt<<<dim3(32, 8),  256, 0, stream>>>(w1, w1T, 256, 1024);
    transpose_cvt<<<dim3(8, 32),  256, 0, stream>>>(w2, w2T, 1024, 256);

    // QKV projection; q/k scale 0.25*sqrt(log2 e); V fused-transposed into vt
    gemm_k<0, 128><<<dim3(NQKV / 128, MM / 128), 256, 0, stream>>>(
        xb, wqkvT, MM, NQKV, 256, nullptr, nullptr, qk, 0.3002806f, vt);

    attn_k<<<dim3(256), 512, 0, stream>>>(qk, vt, attn);

    gemm_k<1, 64><<<dim3(4, MM / 128), 256, 0, stream>>>(
        attn, wuT, MM, 256, 2048, bu, x, y1, 1.0f, nullptr);
    layernorm_k<<<MM / 4, 256, 0, stream>>>(y1, g1, be1, x1, x1b);

    gemm_k<2, 128><<<dim3(8, MM / 128), 256, 0, stream>>>(
        x1b, w1T, MM, 1024, 256, b1, nullptr, hid, 1.0f, nullptr);
    gemm_k<1, 64><<<dim3(4, MM / 128), 256, 0, stream>>>(
        hid, w2T, MM, 256, 1024, b2, x1, y2, 1.0f, nullptr);
    layernorm_k<<<MM / 4, 256, 0, stream>>>(y2, g2, be2, (float*)d_out, nullptr);
}